// Round 11
// baseline (413.896 us; speedup 1.0000x reference)
//
#include <hip/hip_runtime.h>
#include <hip/hip_bf16.h>
#include <hip/hip_fp16.h>

// ---------------- types / helpers ----------------
typedef __attribute__((ext_vector_type(8))) short bf16x8;     // MFMA A/B frag (4 VGPR)
typedef __attribute__((ext_vector_type(4))) float f32x4;      // MFMA C/D frag
typedef __attribute__((ext_vector_type(2))) float f32x2;      // v_pk_*_f32 operand pair
typedef __attribute__((ext_vector_type(4))) unsigned int u32x4;
typedef __attribute__((ext_vector_type(2))) unsigned int u32x2;

#define MFMA_BF16(A,B,C) __builtin_amdgcn_mfma_f32_16x16x32_bf16((A),(B),(C),0,0,0)

static __device__ __forceinline__ unsigned int pkbf2(float a, float b) {
  __hip_bfloat162 h = __float22bfloat162_rn(make_float2(a, b));   // v_cvt_pk_bf16_f32
  unsigned int u; __builtin_memcpy(&u, &h, sizeof(u));
  return u;
}
static __device__ __forceinline__ unsigned short f2bf1(float f) {
  __hip_bfloat16 h = __float2bfloat16(f);
  unsigned short u; __builtin_memcpy(&u, &h, sizeof(u));
  return u;
}
// LDS 16B-unit swizzle hash (row bits 0..5 -> bank spread).
static __device__ __forceinline__ int swz8(int v) { return (v ^ (v >> 3)) & 7; }

// DPP row-rotate (within 16-lane row) — pure VALU.
template<int N>
static __device__ __forceinline__ float rot16(float x) {
  return __builtin_bit_cast(float,
      __builtin_amdgcn_mov_dpp(__builtin_bit_cast(int, x), 0x120 + N, 0xF, 0xF, false));
}
// All-lane sum over the 16 lanes of a DPP row (lanes sharing lane>>4).
static __device__ __forceinline__ float sum16(float x) {
  x += rot16<8>(x);
  x += rot16<4>(x);
  x += rot16<2>(x);
  x += rot16<1>(x);
  return x;
}
template<int N>
static __device__ __forceinline__ f32x2 rot16v2(f32x2 x) {
  f32x2 r; r[0] = rot16<N>(x[0]); r[1] = rot16<N>(x[1]); return r;
}
static __device__ __forceinline__ f32x2 sum16v2(f32x2 x) {   // paired sum16 (pk adds)
  x += rot16v2<8>(x);
  x += rot16v2<4>(x);
  x += rot16v2<2>(x);
  x += rot16v2<1>(x);
  return x;
}

// ---------------- d_ws layout (bytes) ----------------
// [    0,16384) : W_a1  bf16 B-frags [16 frag][64 lane][8 e]  frag f=kt*4+nt
// [16384,32768) : W_out bf16 B-frags same layout
// [32768,36864) : W_encT bf16 A-frags [4 mt][64 lane][8 e]  (k=8*(l>>4)+e, ch=16mt+(l&15); 0 for k>=9)
__global__ void gcn_prep(const float* __restrict__ wa1, const float* __restrict__ wout,
                         const float* __restrict__ wenc,
                         unsigned short* __restrict__ wa1f, unsigned short* __restrict__ woutf,
                         unsigned short* __restrict__ wencT) {
  int i = blockIdx.x * 512 + threadIdx.x;
  if (i < 8192) {
    int e = i & 7, l = (i >> 3) & 63, f = i >> 9;
    int kt = f >> 2, nt = f & 3;
    int k = 32 * kt + 8 * (l >> 4) + e;
    int col = 16 * nt + (l & 15);
    wa1f[i]  = f2bf1(wa1 [k * 64 + col]);
    woutf[i] = f2bf1(wout[k * 64 + col]);
  }
  int j = i - 8192;
  if (j >= 0 && j < 2048) {
    int e = j & 7, l = (j >> 3) & 63, mt = j >> 9;
    int k = 8 * (l >> 4) + e;
    int ch = 16 * mt + (l & 15);
    wencT[j] = (k < 9) ? f2bf1(wenc[k * 64 + ch]) : (unsigned short)0;
  }
}

// ---------------- fused main kernel ----------------
// 16 output rows / block, 256 threads (4 WAVES), grid 8192.
// LDS = 20480 B -> 8 blocks/CU x 4 waves = 32 waves/CU = FULL static occupancy
// (was 16 waves/CU with 2-wave blocks; R10 showed latency-bound w/ 21% stall).
// 3 barriers (E->S/G, G->O, O-sLN). S->G barrierless: sE stable after barrier 1;
// sS[r] writer wave (r>>2) == G reader wave (tid>>4 >>2).
// LDS map (byte offsets):
//   [    0,18432) sE   [144 vec][64 ch] bf16; 16B units swizzled: unit = c8 ^ swz8(v)
//                 vec 0..127 = nbr, 128..143 = cur (row r at 128+r)
//                 sLN (512 B, phase O only) overlays sE vecs 0..3 (dead after G).
//   [18432,20480) sAgg [16 r][64 ch] bf16, swizzled like sE (written in G, read in O)
//                 sS[r] = 32 B f32 weights INSIDE sAgg row r at +((r&3)<<5):
//                 written in S, read at start of G (same wave), then overwritten
//                 by the sAgg store (reads precede writes in-wave).
__global__ __launch_bounds__(256, 8) void gcn_main(
    const float* __restrict__ xcur, const float* __restrict__ xnbr,
    const int*   __restrict__ msk,
    const float* __restrict__ benc, const float* __restrict__ genc, const float* __restrict__ beenc,
    const float* __restrict__ ba1,  const float* __restrict__ wa2,
    const float* __restrict__ bout, const float* __restrict__ gout, const float* __restrict__ beout,
    const unsigned short* __restrict__ wa1f, const unsigned short* __restrict__ woutf,
    const unsigned short* __restrict__ wencT,
    float* __restrict__ out) {

  __shared__ __align__(16) char smem[20480];
  unsigned short* sE   = (unsigned short*)smem;
  unsigned short* sAgg = (unsigned short*)(smem + 18432);
  float*          sLN  = (float*)smem;                 // phase-O overlay on sE vecs 0..3

  const int tid  = threadIdx.x;
  const int w    = tid >> 6;                // wave 0..3
  const int lane = tid & 63;
  const int lm   = lane & 15, g = lane >> 4;
  const int blk  = blockIdx.x;              // 16 output rows, 128 nbr vecs

  // Persisted across phases (prefetched early, used late):
  bf16x8 wf[16];                            // W_a1 frags (loaded before E->S barrier)
  bf16x8 wofc[4];                           // W_out frags for this wave's nt = w (kt 0..3)
  float bov, gvo, bevo;
  float ba1v[4], wa2v[4];
  int4 mkv[2];                              // masks for this wave's 2 score tiles

  // ---------- Phase E: encode 144 vecs via transposed MFMA (D[ch][vec]) ----------
  // Tiles t = w, w+4, w+8 (<=8): wave 0 gets {0,4,8(cur)}, waves 1-3 get 2 nbr tiles.
  {
    bf16x8 ef[4];
    #pragma unroll
    for (int mt = 0; mt < 4; mt++) ef[mt] = *(const bf16x8*)(wencT + (mt * 64 + lane) * 8);
    f32x4 bv[4], gv[4], bev[4];
    #pragma unroll
    for (int mt = 0; mt < 4; mt++) {
      bv[mt]  = *(const f32x4*)(benc  + 16 * mt + 4 * g);
      gv[mt]  = *(const f32x4*)(genc  + 16 * mt + 4 * g);
      bev[mt] = *(const f32x4*)(beenc + 16 * mt + 4 * g);
    }
    #pragma unroll
    for (int nt = 0; nt < 4; nt++) { ba1v[nt] = ba1[16 * nt + lm]; wa2v[nt] = wa2[16 * nt + lm]; }
    float nx[8];
    {
      const float* xb = xnbr + ((size_t)blk * 128 + w * 16 + lm) * 9;   // t=w<8 always nbr
      #pragma unroll
      for (int e = 0; e < 8; e++) nx[e] = 0.f;
      if (g == 0) {
        #pragma unroll
        for (int e = 0; e < 8; e++) nx[e] = xb[e];
      } else if (g == 1) nx[0] = xb[8];
    }
    #pragma unroll
    for (int s5 = 0; s5 < 3; s5++) {
      int t = 4 * s5 + w;
      if (t > 8) break;
      float xv[8];
      #pragma unroll
      for (int e = 0; e < 8; e++) xv[e] = nx[e];
      int tn = t + 4;
      if (tn <= 8) {                        // issue next tile's loads now
        const float* xb = (tn < 8) ? (xnbr + ((size_t)blk * 128 + tn * 16 + lm) * 9)
                                   : (xcur + ((size_t)blk * 16 + lm) * 9);
        #pragma unroll
        for (int e = 0; e < 8; e++) nx[e] = 0.f;
        if (g == 0) {
          #pragma unroll
          for (int e = 0; e < 8; e++) nx[e] = xb[e];
        } else if (g == 1) nx[0] = xb[8];
      }
      int v = (t < 8) ? (t * 16 + lm) : (128 + lm);
      u32x4 bq;
      #pragma unroll
      for (int e2 = 0; e2 < 4; e2++) bq[e2] = pkbf2(xv[2 * e2], xv[2 * e2 + 1]);
      bf16x8 bfr = __builtin_bit_cast(bf16x8, bq);
      f32x4 acc[4];
      #pragma unroll
      for (int mt = 0; mt < 4; mt++) acc[mt] = bv[mt];   // bias folded into MFMA C
      #pragma unroll
      for (int mt = 0; mt < 4; mt++) acc[mt] = MFMA_BF16(ef[mt], bfr, acc[mt]);
      // LN sums via packed-f32 (v_pk_add/v_pk_fma): acc pairs are adjacent VGPRs.
      f32x2 s1v = f32x2{0.f, 0.f}, s2v = f32x2{0.f, 0.f};
      #pragma unroll
      for (int mt = 0; mt < 4; mt++) {
        f32x2 lo; lo[0] = acc[mt][0]; lo[1] = acc[mt][1];
        f32x2 hi; hi[0] = acc[mt][2]; hi[1] = acc[mt][3];
        s1v += lo; s1v += hi;
        s2v = __builtin_elementwise_fma(lo, lo, s2v);
        s2v = __builtin_elementwise_fma(hi, hi, s2v);
      }
      float s1 = s1v[0] + s1v[1], s2 = s2v[0] + s2v[1];
      s1 += __shfl_xor(s1, 16); s1 += __shfl_xor(s1, 32);
      s2 += __shfl_xor(s2, 16); s2 += __shfl_xor(s2, 32);
      float mu = s1 * (1.f / 64.f);
      float rs = rsqrtf(s2 * (1.f / 64.f) - mu * mu + 1e-5f);
      float t0 = -mu * rs;                  // y = fma(fma(h, rs, t0), g, be): 3 ops/ch
      f32x2 rs2; rs2[0] = rs; rs2[1] = rs;
      f32x2 t02; t02[0] = t0; t02[1] = t0;
      int h8 = swz8(v);
      #pragma unroll
      for (int mt = 0; mt < 4; mt++) {
        f32x2 h0; h0[0] = acc[mt][0]; h0[1] = acc[mt][1];
        f32x2 h1; h1[0] = acc[mt][2]; h1[1] = acc[mt][3];
        f32x2 g0; g0[0] = gv[mt][0]; g0[1] = gv[mt][1];
        f32x2 g1; g1[0] = gv[mt][2]; g1[1] = gv[mt][3];
        f32x2 b0; b0[0] = bev[mt][0]; b0[1] = bev[mt][1];
        f32x2 b1; b1[0] = bev[mt][2]; b1[1] = bev[mt][3];
        f32x2 z0 = __builtin_elementwise_fma(h0, rs2, t02);   // v_pk_fma_f32
        f32x2 z1 = __builtin_elementwise_fma(h1, rs2, t02);
        z0 = __builtin_elementwise_fma(z0, g0, b0);
        z1 = __builtin_elementwise_fma(z1, g1, b1);
        float y0 = fmaxf(z0[0], 0.f), y1 = fmaxf(z0[1], 0.f);
        float y2 = fmaxf(z1[0], 0.f), y3 = fmaxf(z1[1], 0.f);
        int unit = (2 * mt + (g >> 1)) ^ h8;
        *(u32x2*)&sE[v * 64 + unit * 8 + ((g & 1) << 2)] = u32x2{pkbf2(y0, y1), pkbf2(y2, y3)};
      }
    }
    // Prefetch phase-S operands so they are in flight across the barrier.
    #pragma unroll
    for (int f = 0; f < 16; f++) wf[f] = *(const bf16x8*)(wa1f + (f * 64 + lane) * 8);
    #pragma unroll
    for (int mm = 0; mm < 2; mm++) {
      int r2 = 4 * w + 2 * mm + (g >> 1);
      mkv[mm] = *(const int4*)(msk + ((size_t)(blk * 16 + r2)) * 8 + 4 * (g & 1));
    }
  }
  __syncthreads();

  // ---------- Phase S: scores + fused masked softmax -> sS weights ----------
  // Wave w owns rows 4w..4w+3 (m = 2w+mm, mm in {0,1}). hc dedup: 16-row MFMA tile
  // with A-row perm vcu(rt) = 128 + 4w + 2*(rt&1) + (rt>>3); lane (g,lm) elem i ->
  // A-row 4g+i -> cur row 4w + 2*(i&1) + (g>>1), so hca[nt][mm] is tile mm's init.
  {
    f32x4 hca[4];
    #pragma unroll
    for (int nt = 0; nt < 4; nt++)
      hca[nt] = f32x4{ba1v[nt], ba1v[nt], ba1v[nt], ba1v[nt]};
    {
      const int vcu = 128 + 4 * w + 2 * (lm & 1) + (lm >> 3), hcu = swz8(vcu);
      #pragma unroll
      for (int ks = 0; ks < 2; ks++) {                   // cur @ W_a1[0:64]
        bf16x8 a = *(const bf16x8*)&sE[vcu * 64 + (((4 * ks + g) ^ hcu) << 3)];
        #pragma unroll
        for (int nt = 0; nt < 4; nt++) hca[nt] = MFMA_BF16(a, wf[ks * 4 + nt], hca[nt]);
      }
    }
    #pragma unroll
    for (int mm = 0; mm < 2; mm++) {
      int m = 2 * w + mm;
      int vb = 16 * m + lm,  hb = swz8(vb);              // nbr row for this lane
      f32x4 a2[4];
      #pragma unroll
      for (int nt = 0; nt < 4; nt++)                     // init = hc + b_a1 (dedup'd)
        a2[nt] = f32x4{hca[nt][mm], hca[nt][mm], hca[nt][mm], hca[nt][mm]};
      #pragma unroll
      for (int ks = 0; ks < 2; ks++) {                   // nbr @ W_a1[64:128]
        bf16x8 a = *(const bf16x8*)&sE[vb * 64 + (((4 * ks + g) ^ hb) << 3)];
        #pragma unroll
        for (int nt = 0; nt < 4; nt++) a2[nt] = MFMA_BF16(a, wf[(2 + ks) * 4 + nt], a2[nt]);
      }
      // relu-dot via pk fma pairs over (i,i+1); per-element order over nt unchanged.
      f32x2 p01 = f32x2{0.f, 0.f}, p23 = f32x2{0.f, 0.f};
      #pragma unroll
      for (int nt = 0; nt < 4; nt++) {
        f32x2 w2; w2[0] = wa2v[nt]; w2[1] = wa2v[nt];
        f32x2 m01; m01[0] = fmaxf(a2[nt][0], 0.f); m01[1] = fmaxf(a2[nt][1], 0.f);
        f32x2 m23; m23[0] = fmaxf(a2[nt][2], 0.f); m23[1] = fmaxf(a2[nt][3], 0.f);
        p01 = __builtin_elementwise_fma(m01, w2, p01);
        p23 = __builtin_elementwise_fma(m23, w2, p23);
      }
      p01 = sum16v2(p01);                   // paired DPP reduce (bit-exact per element)
      p23 = sum16v2(p23);
      float p[4] = {p01[0], p01[1], p23[0], p23[1]};
      const int4 mk = mkv[mm];
      float sc0 = mk.x ? p[0] : -1e30f, sc1 = mk.y ? p[1] : -1e30f;
      float sc2 = mk.z ? p[2] : -1e30f, sc3 = mk.w ? p[3] : -1e30f;
      float mloc = fmaxf(fmaxf(sc0, sc1), fmaxf(sc2, sc3));
      float mx = fmaxf(mloc, __shfl_xor(mloc, 16));   // partner g-half, same row
      float e0 = mk.x ? __expf(sc0 - mx) : 0.f;
      float e1 = mk.y ? __expf(sc1 - mx) : 0.f;
      float e2 = mk.z ? __expf(sc2 - mx) : 0.f;
      float e3 = mk.w ? __expf(sc3 - mx) : 0.f;
      float ss = (e0 + e1) + (e2 + e3);
      ss += __shfl_xor(ss, 16);
      float rinv = (ss > 0.f) ? (1.f / ss) : 0.f;     // all-masked row -> 0
      int r2 = 4 * w + 2 * mm + (g >> 1);
      if (lm == 0)
        *(float4*)(smem + 18432 + r2 * 128 + ((r2 & 3) << 5) + 16 * (g & 1)) =
            make_float4(e0 * rinv, e1 * rinv, e2 * rinv, e3 * rinv);
    }
    // Prefetch phase-O W_out frags (this wave's nt = w) + LN params (wf dead now).
    #pragma unroll
    for (int kt = 0; kt < 4; kt++)
      wofc[kt] = *(const bf16x8*)(woutf + ((kt * 4 + w) * 64 + lane) * 8);
    bov  = bout [16 * w + lm];
    gvo  = gout [16 * w + lm];
    bevo = beout[16 * w + lm];
  }
  // NO barrier: phase G reads only sE (stable since barrier 1) and this wave's
  // own sS rows (r = tid>>4 in [4w, 4w+4), same wave as the S-phase writer).

  // ---------- Phase G: aggregate, thread = (row, 8 B half-unit) ----------
  {
    int r = tid >> 4, u16 = tid & 15;
    int cu = u16 >> 1, half = u16 & 1;
    const char* sSr = smem + 18432 + r * 128 + ((r & 3) << 5);  // sS[r], in-wave RAW
    float4 wA = *(const float4*)sSr;
    float4 wB = *(const float4*)(sSr + 16);
    float wv[8] = {wA.x, wA.y, wA.z, wA.w, wB.x, wB.y, wB.z, wB.w};
    f32x2 av[2];
    #pragma unroll
    for (int e = 0; e < 2; e++) av[e] = f32x2{0.f, 0.f};
    #pragma unroll
    for (int n = 0; n < 8; n++) {
      int v = 8 * r + n;
      u32x2 ev = *(const u32x2*)&sE[v * 64 + (((cu ^ swz8(v)) << 3) + (half << 2))];
      f32x2 wn2; wn2[0] = wv[n]; wn2[1] = wv[n];
      #pragma unroll
      for (int e2 = 0; e2 < 2; e2++) {       // {lo,hi} pair -> one v_pk_fma_f32
        unsigned int u = ev[e2];
        f32x2 lh;
        lh[0] = __builtin_bit_cast(float, u << 16);
        lh[1] = __builtin_bit_cast(float, u & 0xffff0000u);
        av[e2] = __builtin_elementwise_fma(wn2, lh, av[e2]);
      }
    }
    // Overwrites sS[r] region -- safe: this wave's sS reads issued above.
    *(u32x2*)&sAgg[r * 64 + (((cu ^ swz8(r)) << 3) + (half << 2))] =
        u32x2{pkbf2(av[0][0], av[0][1]), pkbf2(av[1][0], av[1][1])};
  }
  __syncthreads();

  // ---------- Phase O: out-proj (K=128), wave w handles nt = w ----------
  // LN partials cross 4 waves via sLN[16 row][4 w] float2 (512 B, overlays sE
  // vecs 0..3, dead after G). Barrier, combine, then full-wave dense store
  // (rows 4g+i, cols 16w+lm) -- same 64 B-chunk footprint as the frozen pattern.
  {
    f32x4 acc = f32x4{bov, bov, bov, bov};               // b_out folded into MFMA C
    const int vc = 128 + lm, hc = swz8(128 + lm);
    #pragma unroll
    for (int ks = 0; ks < 2; ks++) {
      bf16x8 a = *(const bf16x8*)&sE[vc * 64 + (((4 * ks + g) ^ hc) << 3)];
      acc = MFMA_BF16(a, wofc[ks], acc);
    }
    const int hA = swz8(lm);
    #pragma unroll
    for (int ks = 0; ks < 2; ks++) {
      bf16x8 a = *(const bf16x8*)&sAgg[lm * 64 + (((4 * ks + g) ^ hA) << 3)];
      acc = MFMA_BF16(a, wofc[2 + ks], acc);
    }
    float s1[4], s2[4];
    #pragma unroll
    for (int i = 0; i < 4; i++) {
      s1[i] = sum16(acc[i]);                 // partial over this wave's 16 ch
      s2[i] = sum16(acc[i] * acc[i]);
    }
    if (lm == 0) {
      #pragma unroll
      for (int i = 0; i < 4; i++)
        *(float2*)&sLN[((4 * g + i) * 4 + w) * 2] = make_float2(s1[i], s2[i]);
    }
    __syncthreads();
    #pragma unroll
    for (int i = 0; i < 4; i++) {
      float4 q0 = *(const float4*)&sLN[((4 * g + i) * 4 + 0) * 2];   // w=0,1 pairs
      float4 q1 = *(const float4*)&sLN[((4 * g + i) * 4 + 2) * 2];   // w=2,3 pairs
      float S1 = (q0.x + q0.z) + (q1.x + q1.z);
      float S2 = (q0.y + q0.w) + (q1.y + q1.w);
      float mu = S1 * (1.f / 64.f);
      float rs = rsqrtf(S2 * (1.f / 64.f) - mu * mu + 1e-5f);
      size_t orow = (size_t)blk * 16 + 4 * g + i;
      float y = fmaxf(fmaf((acc[i] - mu) * rs, gvo, bevo), 0.f);
      out[orow * 64 + 16 * w + lm] = y;      // all 64 lanes active: dense store
    }
  }
}

// ---------------- launch ----------------
extern "C" void kernel_launch(void* const* d_in, const int* in_sizes, int n_in,
                              void* d_out, int out_size, void* d_ws, size_t ws_size,
                              hipStream_t stream) {
  const float* xcur = (const float*)d_in[0];   // [B,9]
  const float* xnbr = (const float*)d_in[1];   // [B,8,9]
  const int*   msk  = (const int*)  d_in[2];   // [B,8]
  const float* wenc = (const float*)d_in[3];
  const float* benc = (const float*)d_in[4];
  const float* genc = (const float*)d_in[5];
  const float* bee  = (const float*)d_in[6];
  const float* wa1  = (const float*)d_in[7];
  const float* ba1  = (const float*)d_in[8];
  const float* wa2  = (const float*)d_in[9];
  // d_in[10] = b_a2 (softmax-invariant, unused)
  const float* wout = (const float*)d_in[11];
  const float* bo   = (const float*)d_in[12];
  const float* go   = (const float*)d_in[13];
  const float* beo  = (const float*)d_in[14];

  unsigned short* wa1f  = (unsigned short*)d_ws;
  unsigned short* woutf = (unsigned short*)((char*)d_ws + 16384);
  unsigned short* wencT = (unsigned short*)((char*)d_ws + 32768);

  gcn_prep<<<20, 512, 0, stream>>>(wa1, wout, wenc, wa1f, woutf, wencT);
  gcn_main<<<8192, 256, 0, stream>>>(xcur, xnbr, msk, benc, genc, bee, ba1, wa2,
                                     bo, go, beo, wa1f, woutf, wencT, (float*)d_out);
}

// Round 12
// 75.326 us; speedup vs baseline: 5.4947x; 5.4947x over previous
//
#include <hip/hip_runtime.h>
#include <hip/hip_bf16.h>
#include <hip/hip_fp16.h>

// ---------------- types / helpers ----------------
typedef __attribute__((ext_vector_type(8))) short bf16x8;     // MFMA A/B frag (4 VGPR)
typedef __attribute__((ext_vector_type(4))) float f32x4;      // MFMA C/D frag
typedef __attribute__((ext_vector_type(2))) float f32x2;      // v_pk_*_f32 operand pair
typedef __attribute__((ext_vector_type(4))) unsigned int u32x4;
typedef __attribute__((ext_vector_type(2))) unsigned int u32x2;

#define MFMA_BF16(A,B,C) __builtin_amdgcn_mfma_f32_16x16x32_bf16((A),(B),(C),0,0,0)

static __device__ __forceinline__ unsigned int pkbf2(float a, float b) {
  __hip_bfloat162 h = __float22bfloat162_rn(make_float2(a, b));   // v_cvt_pk_bf16_f32
  unsigned int u; __builtin_memcpy(&u, &h, sizeof(u));
  return u;
}
static __device__ __forceinline__ unsigned short f2bf1(float f) {
  __hip_bfloat16 h = __float2bfloat16(f);
  unsigned short u; __builtin_memcpy(&u, &h, sizeof(u));
  return u;
}
// LDS 16B-unit swizzle hash (row bits 0..5 -> bank spread).
static __device__ __forceinline__ int swz8(int v) { return (v ^ (v >> 3)) & 7; }

// DPP row-rotate (within 16-lane row) — pure VALU.
template<int N>
static __device__ __forceinline__ float rot16(float x) {
  return __builtin_bit_cast(float,
      __builtin_amdgcn_mov_dpp(__builtin_bit_cast(int, x), 0x120 + N, 0xF, 0xF, false));
}
// All-lane sum over the 16 lanes of a DPP row (lanes sharing lane>>4).
static __device__ __forceinline__ float sum16(float x) {
  x += rot16<8>(x);
  x += rot16<4>(x);
  x += rot16<2>(x);
  x += rot16<1>(x);
  return x;
}
template<int N>
static __device__ __forceinline__ f32x2 rot16v2(f32x2 x) {
  f32x2 r; r[0] = rot16<N>(x[0]); r[1] = rot16<N>(x[1]); return r;
}
static __device__ __forceinline__ f32x2 sum16v2(f32x2 x) {   // paired sum16 (pk adds)
  x += rot16v2<8>(x);
  x += rot16v2<4>(x);
  x += rot16v2<2>(x);
  x += rot16v2<1>(x);
  return x;
}

// ---------------- d_ws layout (bytes) ----------------
// [    0,16384) : W_a1  bf16 B-frags [16 frag][64 lane][8 e]  frag f=kt*4+nt
// [16384,32768) : W_out bf16 B-frags same layout
// [32768,36864) : W_encT bf16 A-frags [4 mt][64 lane][8 e]  (k=8*(l>>4)+e, ch=16mt+(l&15); 0 for k>=9)
__global__ void gcn_prep(const float* __restrict__ wa1, const float* __restrict__ wout,
                         const float* __restrict__ wenc,
                         unsigned short* __restrict__ wa1f, unsigned short* __restrict__ woutf,
                         unsigned short* __restrict__ wencT) {
  int i = blockIdx.x * 512 + threadIdx.x;
  if (i < 8192) {
    int e = i & 7, l = (i >> 3) & 63, f = i >> 9;
    int kt = f >> 2, nt = f & 3;
    int k = 32 * kt + 8 * (l >> 4) + e;
    int col = 16 * nt + (l & 15);
    wa1f[i]  = f2bf1(wa1 [k * 64 + col]);
    woutf[i] = f2bf1(wout[k * 64 + col]);
  }
  int j = i - 8192;
  if (j >= 0 && j < 2048) {
    int e = j & 7, l = (j >> 3) & 63, mt = j >> 9;
    int k = 8 * (l >> 4) + e;
    int ch = 16 * mt + (l & 15);
    wencT[j] = (k < 9) ? f2bf1(wenc[k * 64 + ch]) : (unsigned short)0;
  }
}

// ---------------- fused main kernel ----------------
// 16 output rows / block, 256 threads (4 WAVES), grid 8192.
// LDS = 20480 B -> up to 8 blocks/CU x 4 waves = 32 waves/CU if VGPR <= 64.
// __launch_bounds__(256, 4): VGPR cap 128. R11's (256,8) forced a 32-VGPR budget
// -> catastrophic scratch spills (FETCH 825 MB, WRITE 1.2 GB). R10 proved this
// state shape compiles to 64 VGPR naturally; give the allocator room, let HW
// occupancy follow (64 VGPR -> 32 waves/CU; 85 -> 24; either > R10's 16).
// 3 barriers (E->S/G, G->O, O-sLN). S->G barrierless: sE stable after barrier 1;
// sS[r] writer wave (r>>2) == G reader wave.
// LDS map (byte offsets):
//   [    0,18432) sE   [144 vec][64 ch] bf16; 16B units swizzled: unit = c8 ^ swz8(v)
//                 vec 0..127 = nbr, 128..143 = cur (row r at 128+r)
//                 sLN (512 B, phase O only) overlays sE vecs 0..3 (dead after G).
//   [18432,20480) sAgg [16 r][64 ch] bf16, swizzled like sE (written in G, read in O)
//                 sS[r] = 32 B f32 weights INSIDE sAgg row r at +((r&3)<<5):
//                 written in S, read at start of G (same wave), then overwritten
//                 by the sAgg store (reads precede writes in-wave).
__global__ __launch_bounds__(256, 4) void gcn_main(
    const float* __restrict__ xcur, const float* __restrict__ xnbr,
    const int*   __restrict__ msk,
    const float* __restrict__ benc, const float* __restrict__ genc, const float* __restrict__ beenc,
    const float* __restrict__ ba1,  const float* __restrict__ wa2,
    const float* __restrict__ bout, const float* __restrict__ gout, const float* __restrict__ beout,
    const unsigned short* __restrict__ wa1f, const unsigned short* __restrict__ woutf,
    const unsigned short* __restrict__ wencT,
    float* __restrict__ out) {

  __shared__ __align__(16) char smem[20480];
  unsigned short* sE   = (unsigned short*)smem;
  unsigned short* sAgg = (unsigned short*)(smem + 18432);
  float*          sLN  = (float*)smem;                 // phase-O overlay on sE vecs 0..3

  const int tid  = threadIdx.x;
  const int w    = tid >> 6;                // wave 0..3
  const int lane = tid & 63;
  const int lm   = lane & 15, g = lane >> 4;
  const int blk  = blockIdx.x;              // 16 output rows, 128 nbr vecs

  // Persisted across phases (prefetched early, used late):
  bf16x8 wf[16];                            // W_a1 frags (loaded before E->S barrier)
  bf16x8 wofc[4];                           // W_out frags for this wave's nt = w (kt 0..3)
  float bov, gvo, bevo;
  float ba1v[4], wa2v[4];
  int4 mkv[2];                              // masks for this wave's 2 score tiles

  // ---------- Phase E: encode 144 vecs via transposed MFMA (D[ch][vec]) ----------
  // Tiles t = w, w+4, w+8 (<=8): wave 0 gets {0,4,8(cur)}, waves 1-3 get 2 nbr tiles.
  {
    bf16x8 ef[4];
    #pragma unroll
    for (int mt = 0; mt < 4; mt++) ef[mt] = *(const bf16x8*)(wencT + (mt * 64 + lane) * 8);
    f32x4 bv[4], gv[4], bev[4];
    #pragma unroll
    for (int mt = 0; mt < 4; mt++) {
      bv[mt]  = *(const f32x4*)(benc  + 16 * mt + 4 * g);
      gv[mt]  = *(const f32x4*)(genc  + 16 * mt + 4 * g);
      bev[mt] = *(const f32x4*)(beenc + 16 * mt + 4 * g);
    }
    #pragma unroll
    for (int nt = 0; nt < 4; nt++) { ba1v[nt] = ba1[16 * nt + lm]; wa2v[nt] = wa2[16 * nt + lm]; }
    float nx[8];
    {
      const float* xb = xnbr + ((size_t)blk * 128 + w * 16 + lm) * 9;   // t=w<8 always nbr
      #pragma unroll
      for (int e = 0; e < 8; e++) nx[e] = 0.f;
      if (g == 0) {
        #pragma unroll
        for (int e = 0; e < 8; e++) nx[e] = xb[e];
      } else if (g == 1) nx[0] = xb[8];
    }
    #pragma unroll
    for (int s5 = 0; s5 < 3; s5++) {
      int t = 4 * s5 + w;
      if (t > 8) break;
      float xv[8];
      #pragma unroll
      for (int e = 0; e < 8; e++) xv[e] = nx[e];
      int tn = t + 4;
      if (tn <= 8) {                        // issue next tile's loads now
        const float* xb = (tn < 8) ? (xnbr + ((size_t)blk * 128 + tn * 16 + lm) * 9)
                                   : (xcur + ((size_t)blk * 16 + lm) * 9);
        #pragma unroll
        for (int e = 0; e < 8; e++) nx[e] = 0.f;
        if (g == 0) {
          #pragma unroll
          for (int e = 0; e < 8; e++) nx[e] = xb[e];
        } else if (g == 1) nx[0] = xb[8];
      }
      int v = (t < 8) ? (t * 16 + lm) : (128 + lm);
      u32x4 bq;
      #pragma unroll
      for (int e2 = 0; e2 < 4; e2++) bq[e2] = pkbf2(xv[2 * e2], xv[2 * e2 + 1]);
      bf16x8 bfr = __builtin_bit_cast(bf16x8, bq);
      f32x4 acc[4];
      #pragma unroll
      for (int mt = 0; mt < 4; mt++) acc[mt] = bv[mt];   // bias folded into MFMA C
      #pragma unroll
      for (int mt = 0; mt < 4; mt++) acc[mt] = MFMA_BF16(ef[mt], bfr, acc[mt]);
      // LN sums via packed-f32 (v_pk_add/v_pk_fma): acc pairs are adjacent VGPRs.
      f32x2 s1v = f32x2{0.f, 0.f}, s2v = f32x2{0.f, 0.f};
      #pragma unroll
      for (int mt = 0; mt < 4; mt++) {
        f32x2 lo; lo[0] = acc[mt][0]; lo[1] = acc[mt][1];
        f32x2 hi; hi[0] = acc[mt][2]; hi[1] = acc[mt][3];
        s1v += lo; s1v += hi;
        s2v = __builtin_elementwise_fma(lo, lo, s2v);
        s2v = __builtin_elementwise_fma(hi, hi, s2v);
      }
      float s1 = s1v[0] + s1v[1], s2 = s2v[0] + s2v[1];
      s1 += __shfl_xor(s1, 16); s1 += __shfl_xor(s1, 32);
      s2 += __shfl_xor(s2, 16); s2 += __shfl_xor(s2, 32);
      float mu = s1 * (1.f / 64.f);
      float rs = rsqrtf(s2 * (1.f / 64.f) - mu * mu + 1e-5f);
      float t0 = -mu * rs;                  // y = fma(fma(h, rs, t0), g, be): 3 ops/ch
      f32x2 rs2; rs2[0] = rs; rs2[1] = rs;
      f32x2 t02; t02[0] = t0; t02[1] = t0;
      int h8 = swz8(v);
      #pragma unroll
      for (int mt = 0; mt < 4; mt++) {
        f32x2 h0; h0[0] = acc[mt][0]; h0[1] = acc[mt][1];
        f32x2 h1; h1[0] = acc[mt][2]; h1[1] = acc[mt][3];
        f32x2 g0; g0[0] = gv[mt][0]; g0[1] = gv[mt][1];
        f32x2 g1; g1[0] = gv[mt][2]; g1[1] = gv[mt][3];
        f32x2 b0; b0[0] = bev[mt][0]; b0[1] = bev[mt][1];
        f32x2 b1; b1[0] = bev[mt][2]; b1[1] = bev[mt][3];
        f32x2 z0 = __builtin_elementwise_fma(h0, rs2, t02);   // v_pk_fma_f32
        f32x2 z1 = __builtin_elementwise_fma(h1, rs2, t02);
        z0 = __builtin_elementwise_fma(z0, g0, b0);
        z1 = __builtin_elementwise_fma(z1, g1, b1);
        float y0 = fmaxf(z0[0], 0.f), y1 = fmaxf(z0[1], 0.f);
        float y2 = fmaxf(z1[0], 0.f), y3 = fmaxf(z1[1], 0.f);
        int unit = (2 * mt + (g >> 1)) ^ h8;
        *(u32x2*)&sE[v * 64 + unit * 8 + ((g & 1) << 2)] = u32x2{pkbf2(y0, y1), pkbf2(y2, y3)};
      }
    }
    // Prefetch phase-S operands so they are in flight across the barrier.
    #pragma unroll
    for (int f = 0; f < 16; f++) wf[f] = *(const bf16x8*)(wa1f + (f * 64 + lane) * 8);
    #pragma unroll
    for (int mm = 0; mm < 2; mm++) {
      int r2 = 4 * w + 2 * mm + (g >> 1);
      mkv[mm] = *(const int4*)(msk + ((size_t)(blk * 16 + r2)) * 8 + 4 * (g & 1));
    }
  }
  __syncthreads();

  // ---------- Phase S: scores + fused masked softmax -> sS weights ----------
  // Wave w owns rows 4w..4w+3 (m = 2w+mm, mm in {0,1}). hc dedup: 16-row MFMA tile
  // with A-row perm vcu(rt) = 128 + 4w + 2*(rt&1) + (rt>>3); lane (g,lm) elem i ->
  // A-row 4g+i -> cur row 4w + 2*(i&1) + (g>>1), so hca[nt][mm] is tile mm's init.
  {
    f32x4 hca[4];
    #pragma unroll
    for (int nt = 0; nt < 4; nt++)
      hca[nt] = f32x4{ba1v[nt], ba1v[nt], ba1v[nt], ba1v[nt]};
    {
      const int vcu = 128 + 4 * w + 2 * (lm & 1) + (lm >> 3), hcu = swz8(vcu);
      #pragma unroll
      for (int ks = 0; ks < 2; ks++) {                   // cur @ W_a1[0:64]
        bf16x8 a = *(const bf16x8*)&sE[vcu * 64 + (((4 * ks + g) ^ hcu) << 3)];
        #pragma unroll
        for (int nt = 0; nt < 4; nt++) hca[nt] = MFMA_BF16(a, wf[ks * 4 + nt], hca[nt]);
      }
    }
    #pragma unroll
    for (int mm = 0; mm < 2; mm++) {
      int m = 2 * w + mm;
      int vb = 16 * m + lm,  hb = swz8(vb);              // nbr row for this lane
      f32x4 a2[4];
      #pragma unroll
      for (int nt = 0; nt < 4; nt++)                     // init = hc + b_a1 (dedup'd)
        a2[nt] = f32x4{hca[nt][mm], hca[nt][mm], hca[nt][mm], hca[nt][mm]};
      #pragma unroll
      for (int ks = 0; ks < 2; ks++) {                   // nbr @ W_a1[64:128]
        bf16x8 a = *(const bf16x8*)&sE[vb * 64 + (((4 * ks + g) ^ hb) << 3)];
        #pragma unroll
        for (int nt = 0; nt < 4; nt++) a2[nt] = MFMA_BF16(a, wf[(2 + ks) * 4 + nt], a2[nt]);
      }
      // relu-dot via pk fma pairs over (i,i+1); per-element order over nt unchanged.
      f32x2 p01 = f32x2{0.f, 0.f}, p23 = f32x2{0.f, 0.f};
      #pragma unroll
      for (int nt = 0; nt < 4; nt++) {
        f32x2 w2; w2[0] = wa2v[nt]; w2[1] = wa2v[nt];
        f32x2 m01; m01[0] = fmaxf(a2[nt][0], 0.f); m01[1] = fmaxf(a2[nt][1], 0.f);
        f32x2 m23; m23[0] = fmaxf(a2[nt][2], 0.f); m23[1] = fmaxf(a2[nt][3], 0.f);
        p01 = __builtin_elementwise_fma(m01, w2, p01);
        p23 = __builtin_elementwise_fma(m23, w2, p23);
      }
      p01 = sum16v2(p01);                   // paired DPP reduce (bit-exact per element)
      p23 = sum16v2(p23);
      float p[4] = {p01[0], p01[1], p23[0], p23[1]};
      const int4 mk = mkv[mm];
      float sc0 = mk.x ? p[0] : -1e30f, sc1 = mk.y ? p[1] : -1e30f;
      float sc2 = mk.z ? p[2] : -1e30f, sc3 = mk.w ? p[3] : -1e30f;
      float mloc = fmaxf(fmaxf(sc0, sc1), fmaxf(sc2, sc3));
      float mx = fmaxf(mloc, __shfl_xor(mloc, 16));   // partner g-half, same row
      float e0 = mk.x ? __expf(sc0 - mx) : 0.f;
      float e1 = mk.y ? __expf(sc1 - mx) : 0.f;
      float e2 = mk.z ? __expf(sc2 - mx) : 0.f;
      float e3 = mk.w ? __expf(sc3 - mx) : 0.f;
      float ss = (e0 + e1) + (e2 + e3);
      ss += __shfl_xor(ss, 16);
      float rinv = (ss > 0.f) ? (1.f / ss) : 0.f;     // all-masked row -> 0
      int r2 = 4 * w + 2 * mm + (g >> 1);
      if (lm == 0)
        *(float4*)(smem + 18432 + r2 * 128 + ((r2 & 3) << 5) + 16 * (g & 1)) =
            make_float4(e0 * rinv, e1 * rinv, e2 * rinv, e3 * rinv);
    }
    // Prefetch phase-O W_out frags (this wave's nt = w) + LN params (wf dead now).
    #pragma unroll
    for (int kt = 0; kt < 4; kt++)
      wofc[kt] = *(const bf16x8*)(woutf + ((kt * 4 + w) * 64 + lane) * 8);
    bov  = bout [16 * w + lm];
    gvo  = gout [16 * w + lm];
    bevo = beout[16 * w + lm];
  }
  // NO barrier: phase G reads only sE (stable since barrier 1) and this wave's
  // own sS rows (r = tid>>4 in [4w, 4w+4), same wave as the S-phase writer).

  // ---------- Phase G: aggregate, thread = (row, 8 B half-unit) ----------
  {
    int r = tid >> 4, u16 = tid & 15;
    int cu = u16 >> 1, half = u16 & 1;
    const char* sSr = smem + 18432 + r * 128 + ((r & 3) << 5);  // sS[r], in-wave RAW
    float4 wA = *(const float4*)sSr;
    float4 wB = *(const float4*)(sSr + 16);
    float wv[8] = {wA.x, wA.y, wA.z, wA.w, wB.x, wB.y, wB.z, wB.w};
    f32x2 av[2];
    #pragma unroll
    for (int e = 0; e < 2; e++) av[e] = f32x2{0.f, 0.f};
    #pragma unroll
    for (int n = 0; n < 8; n++) {
      int v = 8 * r + n;
      u32x2 ev = *(const u32x2*)&sE[v * 64 + (((cu ^ swz8(v)) << 3) + (half << 2))];
      f32x2 wn2; wn2[0] = wv[n]; wn2[1] = wv[n];
      #pragma unroll
      for (int e2 = 0; e2 < 2; e2++) {       // {lo,hi} pair -> one v_pk_fma_f32
        unsigned int u = ev[e2];
        f32x2 lh;
        lh[0] = __builtin_bit_cast(float, u << 16);
        lh[1] = __builtin_bit_cast(float, u & 0xffff0000u);
        av[e2] = __builtin_elementwise_fma(wn2, lh, av[e2]);
      }
    }
    // Overwrites sS[r] region -- safe: this wave's sS reads issued above.
    *(u32x2*)&sAgg[r * 64 + (((cu ^ swz8(r)) << 3) + (half << 2))] =
        u32x2{pkbf2(av[0][0], av[0][1]), pkbf2(av[1][0], av[1][1])};
  }
  __syncthreads();

  // ---------- Phase O: out-proj (K=128), wave w handles nt = w ----------
  // LN partials cross 4 waves via sLN[16 row][4 w] float2 (512 B, overlays sE
  // vecs 0..3, dead after G). Barrier, combine, then full-wave dense store
  // (rows 4g+i, cols 16w+lm) -- same 64 B-chunk footprint as the frozen pattern.
  {
    f32x4 acc = f32x4{bov, bov, bov, bov};               // b_out folded into MFMA C
    const int vc = 128 + lm, hc = swz8(128 + lm);
    #pragma unroll
    for (int ks = 0; ks < 2; ks++) {
      bf16x8 a = *(const bf16x8*)&sE[vc * 64 + (((4 * ks + g) ^ hc) << 3)];
      acc = MFMA_BF16(a, wofc[ks], acc);
    }
    const int hA = swz8(lm);
    #pragma unroll
    for (int ks = 0; ks < 2; ks++) {
      bf16x8 a = *(const bf16x8*)&sAgg[lm * 64 + (((4 * ks + g) ^ hA) << 3)];
      acc = MFMA_BF16(a, wofc[2 + ks], acc);
    }
    float s1[4], s2[4];
    #pragma unroll
    for (int i = 0; i < 4; i++) {
      s1[i] = sum16(acc[i]);                 // partial over this wave's 16 ch
      s2[i] = sum16(acc[i] * acc[i]);
    }
    if (lm == 0) {
      #pragma unroll
      for (int i = 0; i < 4; i++)
        *(float2*)&sLN[((4 * g + i) * 4 + w) * 2] = make_float2(s1[i], s2[i]);
    }
    __syncthreads();
    #pragma unroll
    for (int i = 0; i < 4; i++) {
      float4 q0 = *(const float4*)&sLN[((4 * g + i) * 4 + 0) * 2];   // w=0,1 pairs
      float4 q1 = *(const float4*)&sLN[((4 * g + i) * 4 + 2) * 2];   // w=2,3 pairs
      float S1 = (q0.x + q0.z) + (q1.x + q1.z);
      float S2 = (q0.y + q0.w) + (q1.y + q1.w);
      float mu = S1 * (1.f / 64.f);
      float rs = rsqrtf(S2 * (1.f / 64.f) - mu * mu + 1e-5f);
      size_t orow = (size_t)blk * 16 + 4 * g + i;
      float y = fmaxf(fmaf((acc[i] - mu) * rs, gvo, bevo), 0.f);
      out[orow * 64 + 16 * w + lm] = y;      // all 64 lanes active: dense store
    }
  }
}

// ---------------- launch ----------------
extern "C" void kernel_launch(void* const* d_in, const int* in_sizes, int n_in,
                              void* d_out, int out_size, void* d_ws, size_t ws_size,
                              hipStream_t stream) {
  const float* xcur = (const float*)d_in[0];   // [B,9]
  const float* xnbr = (const float*)d_in[1];   // [B,8,9]
  const int*   msk  = (const int*)  d_in[2];   // [B,8]
  const float* wenc = (const float*)d_in[3];
  const float* benc = (const float*)d_in[4];
  const float* genc = (const float*)d_in[5];
  const float* bee  = (const float*)d_in[6];
  const float* wa1  = (const float*)d_in[7];
  const float* ba1  = (const float*)d_in[8];
  const float* wa2  = (const float*)d_in[9];
  // d_in[10] = b_a2 (softmax-invariant, unused)
  const float* wout = (const float*)d_in[11];
  const float* bo   = (const float*)d_in[12];
  const float* go   = (const float*)d_in[13];
  const float* beo  = (const float*)d_in[14];

  unsigned short* wa1f  = (unsigned short*)d_ws;
  unsigned short* woutf = (unsigned short*)((char*)d_ws + 16384);
  unsigned short* wencT = (unsigned short*)((char*)d_ws + 32768);

  gcn_prep<<<20, 512, 0, stream>>>(wa1, wout, wenc, wa1f, woutf, wencT);
  gcn_main<<<8192, 256, 0, stream>>>(xcur, xnbr, msk, benc, genc, bee, ba1, wa2,
                                     bo, go, beo, wa1f, woutf, wencT, (float*)d_out);
}

// Round 13
// 66.354 us; speedup vs baseline: 6.2377x; 1.1352x over previous
//
#include <hip/hip_runtime.h>
#include <hip/hip_bf16.h>
#include <hip/hip_fp16.h>

// ---------------- types / helpers ----------------
typedef __attribute__((ext_vector_type(8))) short bf16x8;     // MFMA A/B frag (4 VGPR)
typedef __attribute__((ext_vector_type(4))) float f32x4;      // MFMA C/D frag
typedef __attribute__((ext_vector_type(2))) float f32x2;      // v_pk_*_f32 operand pair
typedef __attribute__((ext_vector_type(4))) unsigned int u32x4;
typedef __attribute__((ext_vector_type(2))) unsigned int u32x2;

#define MFMA_BF16(A,B,C) __builtin_amdgcn_mfma_f32_16x16x32_bf16((A),(B),(C),0,0,0)

static __device__ __forceinline__ unsigned int pkbf2(float a, float b) {
  __hip_bfloat162 h = __float22bfloat162_rn(make_float2(a, b));   // v_cvt_pk_bf16_f32
  unsigned int u; __builtin_memcpy(&u, &h, sizeof(u));
  return u;
}
static __device__ __forceinline__ unsigned short f2bf1(float f) {
  __hip_bfloat16 h = __float2bfloat16(f);
  unsigned short u; __builtin_memcpy(&u, &h, sizeof(u));
  return u;
}
// LDS 16B-unit swizzle hash (row bits 0..5 -> bank spread).
static __device__ __forceinline__ int swz8(int v) { return (v ^ (v >> 3)) & 7; }

// DPP row-rotate (within 16-lane row) — pure VALU.
template<int N>
static __device__ __forceinline__ float rot16(float x) {
  return __builtin_bit_cast(float,
      __builtin_amdgcn_mov_dpp(__builtin_bit_cast(int, x), 0x120 + N, 0xF, 0xF, false));
}
// All-lane sum over the 16 lanes of a DPP row (lanes sharing lane>>4).
static __device__ __forceinline__ float sum16(float x) {
  x += rot16<8>(x);
  x += rot16<4>(x);
  x += rot16<2>(x);
  x += rot16<1>(x);
  return x;
}
template<int N>
static __device__ __forceinline__ f32x2 rot16v2(f32x2 x) {
  f32x2 r; r[0] = rot16<N>(x[0]); r[1] = rot16<N>(x[1]); return r;
}
static __device__ __forceinline__ f32x2 sum16v2(f32x2 x) {   // paired sum16 (pk adds)
  x += rot16v2<8>(x);
  x += rot16v2<4>(x);
  x += rot16v2<2>(x);
  x += rot16v2<1>(x);
  return x;
}

// ---------------- d_ws layout (bytes) ----------------
// [    0,16384) : W_a1  bf16 B-frags [16 frag][64 lane][8 e]  frag f=kt*4+nt
// [16384,32768) : W_out bf16 B-frags same layout
// [32768,36864) : W_encT bf16 A-frags [4 mt][64 lane][8 e]  (k=8*(l>>4)+e, ch=16mt+(l&15); 0 for k>=9)
__global__ void gcn_prep(const float* __restrict__ wa1, const float* __restrict__ wout,
                         const float* __restrict__ wenc,
                         unsigned short* __restrict__ wa1f, unsigned short* __restrict__ woutf,
                         unsigned short* __restrict__ wencT) {
  int i = blockIdx.x * 512 + threadIdx.x;
  if (i < 8192) {
    int e = i & 7, l = (i >> 3) & 63, f = i >> 9;
    int kt = f >> 2, nt = f & 3;
    int k = 32 * kt + 8 * (l >> 4) + e;
    int col = 16 * nt + (l & 15);
    wa1f[i]  = f2bf1(wa1 [k * 64 + col]);
    woutf[i] = f2bf1(wout[k * 64 + col]);
  }
  int j = i - 8192;
  if (j >= 0 && j < 2048) {
    int e = j & 7, l = (j >> 3) & 63, mt = j >> 9;
    int k = 8 * (l >> 4) + e;
    int ch = 16 * mt + (l & 15);
    wencT[j] = (k < 9) ? f2bf1(wenc[k * 64 + ch]) : (unsigned short)0;
  }
}

// ---------------- fused main kernel ----------------
// 16 output rows / block, 128 threads (2 waves), grid 8192.  == R10 structure ==
// (R11/R12 proved 4-wave blocks are worse: 2x per-block fixed overhead + wider
// barrier coupling; R1 proved 1-wave is worse. 2-wave/16-row is the optimum.)
// + T5 s_setprio around MFMA clusters: 8 independent blocks/CU sit at staggered
// phases (attn-like regime where setprio measured +4-7%); prioritize the wave
// feeding the matrix pipe over waves in VALU epilogues.
// LDS = 20480 B exactly -> 8 blocks/CU. 3 barriers (E->S/G, G->O, O-sLN).
// LDS map: see R6 comments (unchanged).
__global__ __launch_bounds__(128, 4) void gcn_main(
    const float* __restrict__ xcur, const float* __restrict__ xnbr,
    const int*   __restrict__ msk,
    const float* __restrict__ benc, const float* __restrict__ genc, const float* __restrict__ beenc,
    const float* __restrict__ ba1,  const float* __restrict__ wa2,
    const float* __restrict__ bout, const float* __restrict__ gout, const float* __restrict__ beout,
    const unsigned short* __restrict__ wa1f, const unsigned short* __restrict__ woutf,
    const unsigned short* __restrict__ wencT,
    float* __restrict__ out) {

  __shared__ __align__(16) char smem[20480];
  unsigned short* sE   = (unsigned short*)smem;
  unsigned short* sAgg = (unsigned short*)(smem + 18432);
  float*          sLN  = (float*)smem;                 // phase-O overlay on sE rows 0..1

  const int tid  = threadIdx.x;
  const int w    = tid >> 6;
  const int lane = tid & 63;
  const int lm   = lane & 15, g = lane >> 4;
  const int blk  = blockIdx.x;              // 16 output rows, 128 nbr vecs

  // Persisted across phases (prefetched early, used late):
  bf16x8 wf[16];                            // W_a1 frags (loaded before E->S barrier)
  bf16x8 wof[8];                            // W_out frags, this wave's nt pair (loaded in S)
  float bov[2], gvo[2], bevo[2];
  float ba1v[4], wa2v[4];
  int4 mkv[4];                              // masks for this wave's 4 score tiles

  // ---------- Phase E: encode 144 vecs via transposed MFMA (D[ch][vec]) ----------
  {
    bf16x8 ef[4];
    #pragma unroll
    for (int mt = 0; mt < 4; mt++) ef[mt] = *(const bf16x8*)(wencT + (mt * 64 + lane) * 8);
    f32x4 bv[4], gv[4], bev[4];
    #pragma unroll
    for (int mt = 0; mt < 4; mt++) {
      bv[mt]  = *(const f32x4*)(benc  + 16 * mt + 4 * g);
      gv[mt]  = *(const f32x4*)(genc  + 16 * mt + 4 * g);
      bev[mt] = *(const f32x4*)(beenc + 16 * mt + 4 * g);
    }
    #pragma unroll
    for (int nt = 0; nt < 4; nt++) { ba1v[nt] = ba1[16 * nt + lm]; wa2v[nt] = wa2[16 * nt + lm]; }
    // 2-deep x prefetch pipeline over this wave's tiles: t = w, w+2, ... (<=8)
    float nx[8];
    {
      const float* xb = (w < 8) ? (xnbr + ((size_t)blk * 128 + w * 16 + lm) * 9)
                                : (xcur + ((size_t)blk * 16 + lm) * 9);
      #pragma unroll
      for (int e = 0; e < 8; e++) nx[e] = 0.f;
      if (g == 0) {
        #pragma unroll
        for (int e = 0; e < 8; e++) nx[e] = xb[e];
      } else if (g == 1) nx[0] = xb[8];
    }
    #pragma unroll
    for (int s5 = 0; s5 < 5; s5++) {
      int t = 2 * s5 + w;
      if (t > 8) break;
      float xv[8];
      #pragma unroll
      for (int e = 0; e < 8; e++) xv[e] = nx[e];
      int tn = t + 2;
      if (tn <= 8) {                        // issue next tile's loads now
        const float* xb = (tn < 8) ? (xnbr + ((size_t)blk * 128 + tn * 16 + lm) * 9)
                                   : (xcur + ((size_t)blk * 16 + lm) * 9);
        #pragma unroll
        for (int e = 0; e < 8; e++) nx[e] = 0.f;
        if (g == 0) {
          #pragma unroll
          for (int e = 0; e < 8; e++) nx[e] = xb[e];
        } else if (g == 1) nx[0] = xb[8];
      }
      int v = (t < 8) ? (t * 16 + lm) : (128 + lm);
      u32x4 bq;
      #pragma unroll
      for (int e2 = 0; e2 < 4; e2++) bq[e2] = pkbf2(xv[2 * e2], xv[2 * e2 + 1]);
      bf16x8 bfr = __builtin_bit_cast(bf16x8, bq);
      f32x4 acc[4];
      #pragma unroll
      for (int mt = 0; mt < 4; mt++) acc[mt] = bv[mt];   // bias folded into MFMA C
      __builtin_amdgcn_s_setprio(1);                     // T5: MFMA cluster
      #pragma unroll
      for (int mt = 0; mt < 4; mt++) acc[mt] = MFMA_BF16(ef[mt], bfr, acc[mt]);
      __builtin_amdgcn_s_setprio(0);
      // LN sums via packed-f32 (v_pk_add/v_pk_fma): acc pairs are adjacent VGPRs.
      f32x2 s1v = f32x2{0.f, 0.f}, s2v = f32x2{0.f, 0.f};
      #pragma unroll
      for (int mt = 0; mt < 4; mt++) {
        f32x2 lo; lo[0] = acc[mt][0]; lo[1] = acc[mt][1];
        f32x2 hi; hi[0] = acc[mt][2]; hi[1] = acc[mt][3];
        s1v += lo; s1v += hi;
        s2v = __builtin_elementwise_fma(lo, lo, s2v);
        s2v = __builtin_elementwise_fma(hi, hi, s2v);
      }
      float s1 = s1v[0] + s1v[1], s2 = s2v[0] + s2v[1];
      s1 += __shfl_xor(s1, 16); s1 += __shfl_xor(s1, 32);
      s2 += __shfl_xor(s2, 16); s2 += __shfl_xor(s2, 32);
      float mu = s1 * (1.f / 64.f);
      float rs = rsqrtf(s2 * (1.f / 64.f) - mu * mu + 1e-5f);
      float t0 = -mu * rs;                  // y = fma(fma(h, rs, t0), g, be): 3 ops/ch
      f32x2 rs2; rs2[0] = rs; rs2[1] = rs;
      f32x2 t02; t02[0] = t0; t02[1] = t0;
      int h8 = swz8(v);
      #pragma unroll
      for (int mt = 0; mt < 4; mt++) {
        f32x2 h0; h0[0] = acc[mt][0]; h0[1] = acc[mt][1];
        f32x2 h1; h1[0] = acc[mt][2]; h1[1] = acc[mt][3];
        f32x2 g0; g0[0] = gv[mt][0]; g0[1] = gv[mt][1];
        f32x2 g1; g1[0] = gv[mt][2]; g1[1] = gv[mt][3];
        f32x2 b0; b0[0] = bev[mt][0]; b0[1] = bev[mt][1];
        f32x2 b1; b1[0] = bev[mt][2]; b1[1] = bev[mt][3];
        f32x2 z0 = __builtin_elementwise_fma(h0, rs2, t02);   // v_pk_fma_f32
        f32x2 z1 = __builtin_elementwise_fma(h1, rs2, t02);
        z0 = __builtin_elementwise_fma(z0, g0, b0);
        z1 = __builtin_elementwise_fma(z1, g1, b1);
        float y0 = fmaxf(z0[0], 0.f), y1 = fmaxf(z0[1], 0.f);
        float y2 = fmaxf(z1[0], 0.f), y3 = fmaxf(z1[1], 0.f);
        int unit = (2 * mt + (g >> 1)) ^ h8;
        *(u32x2*)&sE[v * 64 + unit * 8 + ((g & 1) << 2)] = u32x2{pkbf2(y0, y1), pkbf2(y2, y3)};
      }
    }
    // Prefetch phase-S operands so they are in flight across the barrier.
    #pragma unroll
    for (int f = 0; f < 16; f++) wf[f] = *(const bf16x8*)(wa1f + (f * 64 + lane) * 8);
    #pragma unroll
    for (int mm = 0; mm < 4; mm++) {
      int r2 = 8 * w + 2 * mm + (g >> 1);
      mkv[mm] = *(const int4*)(msk + ((size_t)(blk * 16 + r2)) * 8 + 4 * (g & 1));
    }
  }
  __syncthreads();

  // ---------- Phase S: scores + fused masked softmax -> sS weights ----------
  // hc dedup: cur@W_a1[0:64]+b_a1 computed ONCE per wave with pre-permuted A-rows
  // so lane (g,lm)'s hca[nt][i] IS hc[8w + 2i + (g>>1)][16nt+lm].
  {
    f32x4 hca[4];
    #pragma unroll
    for (int nt = 0; nt < 4; nt++)
      hca[nt] = f32x4{ba1v[nt], ba1v[nt], ba1v[nt], ba1v[nt]};
    {
      const int vcu = 128 + 8 * w + 2 * (lm & 3) + (lm >> 3), hcu = swz8(vcu);
      __builtin_amdgcn_s_setprio(1);                     // T5: MFMA cluster
      #pragma unroll
      for (int ks = 0; ks < 2; ks++) {                   // cur @ W_a1[0:64]
        bf16x8 a = *(const bf16x8*)&sE[vcu * 64 + (((4 * ks + g) ^ hcu) << 3)];
        #pragma unroll
        for (int nt = 0; nt < 4; nt++) hca[nt] = MFMA_BF16(a, wf[ks * 4 + nt], hca[nt]);
      }
      __builtin_amdgcn_s_setprio(0);
    }
    #pragma unroll
    for (int mm = 0; mm < 4; mm++) {
      int m = 4 * w + mm;
      int vb = 16 * m + lm,  hb = swz8(vb);              // nbr row for this lane
      f32x4 a2[4];
      #pragma unroll
      for (int nt = 0; nt < 4; nt++)                     // init = hc + b_a1 (dedup'd)
        a2[nt] = f32x4{hca[nt][mm], hca[nt][mm], hca[nt][mm], hca[nt][mm]};
      __builtin_amdgcn_s_setprio(1);                     // T5: MFMA cluster
      #pragma unroll
      for (int ks = 0; ks < 2; ks++) {                   // nbr @ W_a1[64:128]
        bf16x8 a = *(const bf16x8*)&sE[vb * 64 + (((4 * ks + g) ^ hb) << 3)];
        #pragma unroll
        for (int nt = 0; nt < 4; nt++) a2[nt] = MFMA_BF16(a, wf[(2 + ks) * 4 + nt], a2[nt]);
      }
      __builtin_amdgcn_s_setprio(0);
      // relu-dot via pk fma pairs over (i,i+1); per-element order over nt unchanged.
      f32x2 p01 = f32x2{0.f, 0.f}, p23 = f32x2{0.f, 0.f};
      #pragma unroll
      for (int nt = 0; nt < 4; nt++) {
        f32x2 w2; w2[0] = wa2v[nt]; w2[1] = wa2v[nt];
        f32x2 m01; m01[0] = fmaxf(a2[nt][0], 0.f); m01[1] = fmaxf(a2[nt][1], 0.f);
        f32x2 m23; m23[0] = fmaxf(a2[nt][2], 0.f); m23[1] = fmaxf(a2[nt][3], 0.f);
        p01 = __builtin_elementwise_fma(m01, w2, p01);
        p23 = __builtin_elementwise_fma(m23, w2, p23);
      }
      p01 = sum16v2(p01);                   // paired DPP reduce (bit-exact per element)
      p23 = sum16v2(p23);
      float p[4] = {p01[0], p01[1], p23[0], p23[1]};
      const int4 mk = mkv[mm];
      float sc0 = mk.x ? p[0] : -1e30f, sc1 = mk.y ? p[1] : -1e30f;
      float sc2 = mk.z ? p[2] : -1e30f, sc3 = mk.w ? p[3] : -1e30f;
      float mloc = fmaxf(fmaxf(sc0, sc1), fmaxf(sc2, sc3));
      float mx = fmaxf(mloc, __shfl_xor(mloc, 16));   // partner g-half, same row
      float e0 = mk.x ? __expf(sc0 - mx) : 0.f;
      float e1 = mk.y ? __expf(sc1 - mx) : 0.f;
      float e2 = mk.z ? __expf(sc2 - mx) : 0.f;
      float e3 = mk.w ? __expf(sc3 - mx) : 0.f;
      float ss = (e0 + e1) + (e2 + e3);
      ss += __shfl_xor(ss, 16);
      float rinv = (ss > 0.f) ? (1.f / ss) : 0.f;     // all-masked row -> 0
      int r2 = 8 * w + 2 * mm + (g >> 1);
      if (lm == 0)
        *(float4*)(smem + 18432 + r2 * 128 + ((r2 & 3) << 5) + 16 * (g & 1)) =
            make_float4(e0 * rinv, e1 * rinv, e2 * rinv, e3 * rinv);
    }
    // Prefetch phase-O W_out frags (this wave's nt pair) + LN params (wf dead now).
    const int nt0 = 2 * w;
    #pragma unroll
    for (int kt = 0; kt < 4; kt++)
      #pragma unroll
      for (int j = 0; j < 2; j++)
        wof[kt * 2 + j] = *(const bf16x8*)(woutf + ((kt * 4 + nt0 + j) * 64 + lane) * 8);
    #pragma unroll
    for (int j = 0; j < 2; j++) {
      bov[j]  = bout [16 * (nt0 + j) + lm];
      gvo[j]  = gout [16 * (nt0 + j) + lm];
      bevo[j] = beout[16 * (nt0 + j) + lm];
    }
  }
  // NO barrier here: phase G reads only sE (stable since barrier 1) and this
  // wave's own sS rows (in-wave DS RAW: r = tid>>3 in [8w, 8w+8)).

  // ---------- Phase G: aggregate, thread = (row, 8-ch unit) ----------
  {
    int r = tid >> 3, cu = tid & 7;
    const char* sSr = smem + 18432 + r * 128 + ((r & 3) << 5);  // sS[r], in-wave RAW
    float4 wA = *(const float4*)sSr;
    float4 wB = *(const float4*)(sSr + 16);
    float wv[8] = {wA.x, wA.y, wA.z, wA.w, wB.x, wB.y, wB.z, wB.w};
    f32x2 av[4];
    #pragma unroll
    for (int e = 0; e < 4; e++) av[e] = f32x2{0.f, 0.f};
    #pragma unroll
    for (int n = 0; n < 8; n++) {
      int v = 8 * r + n;
      u32x4 ev = *(const u32x4*)&sE[v * 64 + ((cu ^ swz8(v)) << 3)];
      f32x2 wn2; wn2[0] = wv[n]; wn2[1] = wv[n];
      #pragma unroll
      for (int e2 = 0; e2 < 4; e2++) {       // {lo,hi} pair -> one v_pk_fma_f32
        unsigned int u = ev[e2];
        f32x2 lh;
        lh[0] = __builtin_bit_cast(float, u << 16);
        lh[1] = __builtin_bit_cast(float, u & 0xffff0000u);
        av[e2] = __builtin_elementwise_fma(wn2, lh, av[e2]);
      }
    }
    // Overwrites sS[r] region -- safe: this wave's sS reads issued above.
    *(u32x4*)&sAgg[r * 64 + ((cu ^ swz8(r)) << 3)] =
        u32x4{pkbf2(av[0][0], av[0][1]), pkbf2(av[1][0], av[1][1]),
              pkbf2(av[2][0], av[2][1]), pkbf2(av[3][0], av[3][1])};
  }
  __syncthreads();

  // ---------- Phase O: out-proj (K=128), wave w handles nt = {2w, 2w+1} ----------
  // FROZEN from round 3: exact store pattern + sLN + barrier (WRITE_SIZE == output).
  {
    const int nt0 = 2 * w;
    f32x4 acc[2];
    #pragma unroll
    for (int j = 0; j < 2; j++)                          // b_out folded into MFMA C
      acc[j] = f32x4{bov[j], bov[j], bov[j], bov[j]};
    const int vc = 128 + lm, hc = swz8(128 + lm);
    __builtin_amdgcn_s_setprio(1);                       // T5: MFMA cluster
    #pragma unroll
    for (int ks = 0; ks < 2; ks++) {
      bf16x8 a = *(const bf16x8*)&sE[vc * 64 + (((4 * ks + g) ^ hc) << 3)];
      #pragma unroll
      for (int j = 0; j < 2; j++) acc[j] = MFMA_BF16(a, wof[ks * 2 + j], acc[j]);
    }
    const int hA = swz8(lm);
    #pragma unroll
    for (int ks = 0; ks < 2; ks++) {
      bf16x8 a = *(const bf16x8*)&sAgg[lm * 64 + (((4 * ks + g) ^ hA) << 3)];
      #pragma unroll
      for (int j = 0; j < 2; j++) acc[j] = MFMA_BF16(a, wof[(2 + ks) * 2 + j], acc[j]);
    }
    __builtin_amdgcn_s_setprio(0);
    float s1[4], s2[4];
    #pragma unroll
    for (int i = 0; i < 4; i++) {
      s1[i] = acc[0][i] + acc[1][i];
      s2[i] = fmaf(acc[0][i], acc[0][i], acc[1][i] * acc[1][i]);
      s1[i] = sum16(s1[i]);                // DPP reduce
      s2[i] = sum16(s2[i]);
    }
    if (lm == 0) {
      #pragma unroll
      for (int i = 0; i < 4; i++)
        *(float2*)&sLN[(4 * g + i) * 4 + 2 * w] = make_float2(s1[i], s2[i]);
    }
    __syncthreads();
    #pragma unroll
    for (int i = 0; i < 4; i++) {
      float2 pa = *(const float2*)&sLN[(4 * g + i) * 4];
      float2 pb = *(const float2*)&sLN[(4 * g + i) * 4 + 2];
      float S1 = pa.x + pb.x, S2 = pa.y + pb.y;
      float mu = S1 * (1.f / 64.f);
      float rs = rsqrtf(S2 * (1.f / 64.f) - mu * mu + 1e-5f);
      size_t orow = (size_t)blk * 16 + 4 * g + i;
      #pragma unroll
      for (int j = 0; j < 2; j++) {
        float y = fmaxf(fmaf((acc[j][i] - mu) * rs, gvo[j], bevo[j]), 0.f);
        out[orow * 64 + 16 * (nt0 + j) + lm] = y;
      }
    }
  }
}

// ---------------- launch ----------------
extern "C" void kernel_launch(void* const* d_in, const int* in_sizes, int n_in,
                              void* d_out, int out_size, void* d_ws, size_t ws_size,
                              hipStream_t stream) {
  const float* xcur = (const float*)d_in[0];   // [B,9]
  const float* xnbr = (const float*)d_in[1];   // [B,8,9]
  const int*   msk  = (const int*)  d_in[2];   // [B,8]
  const float* wenc = (const float*)d_in[3];
  const float* benc = (const float*)d_in[4];
  const float* genc = (const float*)d_in[5];
  const float* bee  = (const float*)d_in[6];
  const float* wa1  = (const float*)d_in[7];
  const float* ba1  = (const float*)d_in[8];
  const float* wa2  = (const float*)d_in[9];
  // d_in[10] = b_a2 (softmax-invariant, unused)
  const float* wout = (const float*)d_in[11];
  const float* bo   = (const float*)d_in[12];
  const float* go   = (const float*)d_in[13];
  const float* beo  = (const float*)d_in[14];

  unsigned short* wa1f  = (unsigned short*)d_ws;
  unsigned short* woutf = (unsigned short*)((char*)d_ws + 16384);
  unsigned short* wencT = (unsigned short*)((char*)d_ws + 32768);

  gcn_prep<<<20, 512, 0, stream>>>(wa1, wout, wenc, wa1f, woutf, wencT);
  gcn_main<<<8192, 128, 0, stream>>>(xcur, xnbr, msk, benc, genc, bee, ba1, wa2,
                                     bo, go, beo, wa1f, woutf, wencT, (float*)d_out);
}